// Round 13
// baseline (317.874 us; speedup 1.0000x reference)
//
#include <hip/hip_runtime.h>
#include <cfloat>

#define B_N 65536
#define D_N 128
#define K_N 4096
#define NKT (K_N / 64)
#define NOUTB ((B_N * D_N) / 1024)   // k_output blocks = 8192

// 2-term split-bf16 fast score (proven R7-R11): t_fast = e2 - 2*(xhi+xlo)·ehi.
// Margin covers np-f32 grid tie window (~3.2e-5) + dropped x·elo term (>10 sigma).
#define FAST_MARGIN 1e-4f
#define CAP 768

typedef __bf16 bf16x8 __attribute__((ext_vector_type(8)));
typedef float  f32x4  __attribute__((ext_vector_type(4)));

// ---------------- workspace layout (bytes) ----------------
static constexpr size_t WS_E2D   = 0;                           // double[K_N]
static constexpr size_t WS_E2F   = WS_E2D + 8 * (size_t)K_N;    // float[K_N]
static constexpr size_t WS_PART  = WS_E2F + 4 * (size_t)K_N;    // double[NOUTB]
static constexpr size_t WS_EPREP = WS_PART + 8 * (size_t)NOUTB; // 64 tiles x 16KB
static constexpr size_t WS_NEED  = WS_EPREP + (size_t)NKT * 16384;

// correctly-rounded f32 ops emulated via f64 (uncontractible)
__device__ __forceinline__ float f32mul(float a, float b) { return (float)((double)a * (double)b); }
__device__ __forceinline__ float f32add(float a, float b) { return (float)((double)a + (double)b); }
__device__ __forceinline__ float f32sub(float a, float b) { return (float)((double)a - (double)b); }

// monotone float<->uint key (no NaNs in scores)
__device__ __forceinline__ unsigned fkey(float f) {
    unsigned u = __float_as_uint(f);
    return (u & 0x80000000u) ? ~u : (u | 0x80000000u);
}
__device__ __forceinline__ float finv(unsigned k) {
    return __uint_as_float((k & 0x80000000u) ? (k ^ 0x80000000u) : ~k);
}

__device__ __forceinline__ void casMin64(unsigned long long* p, unsigned long long v) {
    unsigned long long old = *p;
    while (v < old) {
        unsigned long long prev = atomicCAS(p, old, v);
        if (prev == old) break;
        old = prev;
    }
}

// numpy einsum SSE-order f32 dot emulation + final score (proven exact vs np)
__device__ __forceinline__ float np_score(const float4* __restrict__ xr,
                                          const float4* __restrict__ er,
                                          float x2, float e2) {
    float l0 = 0.f, l1 = 0.f, l2 = 0.f, l3 = 0.f;
#pragma unroll
    for (int f = 0; f < 32; ++f) {
        float4 xv = xr[f];
        float4 ev = er[f];
        l0 = f32add(l0, f32mul(xv.x, ev.x));
        l1 = f32add(l1, f32mul(xv.y, ev.y));
        l2 = f32add(l2, f32mul(xv.z, ev.z));
        l3 = f32add(l3, f32mul(xv.w, ev.w));
    }
    float xe = f32add(f32add(l0, l2), f32add(l1, l3));
    float S  = f32sub(x2, 2.0f * xe);
    return f32add(S, e2);
}

// ---------------- kernel 1: e2 (f64 + f32) ----------------
__global__ void k_setup(const float* __restrict__ e, double* __restrict__ e2d,
                        float* __restrict__ e2f, int full) {
    int k = blockIdx.x * blockDim.x + threadIdx.x;
    if (k < K_N) {
        const float* row = e + (size_t)k * D_N;
        double s = 0.0;
        for (int d = 0; d < D_N; ++d) { double v = (double)row[d]; s += v * v; }
        e2d[k] = s;
        if (full) e2f[k] = (float)s;
    }
}

// ---------------- kernel 1c: E -> bf16-hi fragments in per-lane order -------
// addr(kt, w, c, lane) = kt*16384 + w*4096 + c*1024 + lane*16. (proven R8-R11)
__global__ void k_prep_e(const float* __restrict__ e, unsigned char* __restrict__ eprep) {
    const int g = blockIdx.x * 256 + threadIdx.x;   // one 16B chunk; 65536 total
    const int kt   = g >> 10;
    const int q    = g & 1023;
    const int w    = q >> 8;
    const int c    = (q >> 6) & 3;
    const int lane = q & 63;
    const int r  = kt * 64 + w * 16 + (lane & 15);
    const int d0 = c * 32 + (lane >> 4) * 8;
    const float* src = e + (size_t)r * D_N + d0;
    float4 a = *(const float4*)src;
    float4 b = *(const float4*)(src + 4);
    bf16x8 h;
    h[0] = (__bf16)a.x; h[1] = (__bf16)a.y; h[2] = (__bf16)a.z; h[3] = (__bf16)a.w;
    h[4] = (__bf16)b.x; h[5] = (__bf16)b.y; h[6] = (__bf16)b.z; h[7] = (__bf16)b.w;
    *(bf16x8*)(eprep + (size_t)g * 16) = h;
}

#define MFMA_BF16 __builtin_amdgcn_mfma_f32_16x16x32_bf16

// one K-tile step: consume CUR fragments, prefetch into NXT (role-swap unroll).
// ZERO-init accs (R9 latency structure: e2 load issued at top, consumed only
// in the epilogue, hidden behind 16 MFMAs). Fold-every-4 + guarded appends.
#define TILE_STEP(C0, C1, C2, C3, N0, N1, N2, N3, KT)                               \
    do {                                                                            \
        const int k0 = (KT) * 64 + w * 16;                                          \
        float4 e2v = *(const float4*)(e2f + k0 + lq * 4);                           \
        if ((KT) + 1 < NKT) {                                                       \
            const unsigned char* bp = ebase + (size_t)((KT) + 1) * 16384;           \
            N0 = *(const bf16x8*)(bp);                                              \
            N1 = *(const bf16x8*)(bp + 1024);                                       \
            N2 = *(const bf16x8*)(bp + 2048);                                       \
            N3 = *(const bf16x8*)(bp + 3072);                                       \
        }                                                                           \
        f32x4 a0 = {}, a1 = {};                                                     \
        a0 = MFMA_BF16(C0, bxh[0][0], a0, 0, 0, 0);                                 \
        a1 = MFMA_BF16(C0, bxh[1][0], a1, 0, 0, 0);                                 \
        a0 = MFMA_BF16(C0, bxl[0][0], a0, 0, 0, 0);                                 \
        a1 = MFMA_BF16(C0, bxl[1][0], a1, 0, 0, 0);                                 \
        a0 = MFMA_BF16(C1, bxh[0][1], a0, 0, 0, 0);                                 \
        a1 = MFMA_BF16(C1, bxh[1][1], a1, 0, 0, 0);                                 \
        a0 = MFMA_BF16(C1, bxl[0][1], a0, 0, 0, 0);                                 \
        a1 = MFMA_BF16(C1, bxl[1][1], a1, 0, 0, 0);                                 \
        a0 = MFMA_BF16(C2, bxh[0][2], a0, 0, 0, 0);                                 \
        a1 = MFMA_BF16(C2, bxh[1][2], a1, 0, 0, 0);                                 \
        a0 = MFMA_BF16(C2, bxl[0][2], a0, 0, 0, 0);                                 \
        a1 = MFMA_BF16(C2, bxl[1][2], a1, 0, 0, 0);                                 \
        a0 = MFMA_BF16(C3, bxh[0][3], a0, 0, 0, 0);                                 \
        a1 = MFMA_BF16(C3, bxh[1][3], a1, 0, 0, 0);                                 \
        a0 = MFMA_BF16(C3, bxl[0][3], a0, 0, 0, 0);                                 \
        a1 = MFMA_BF16(C3, bxl[1][3], a1, 0, 0, 0);                                 \
        float t00 = fmaf(2.0f, a0[0], e2v.x);                                       \
        float t01 = fmaf(2.0f, a0[1], e2v.y);                                       \
        float t02 = fmaf(2.0f, a0[2], e2v.z);                                       \
        float t03 = fmaf(2.0f, a0[3], e2v.w);                                       \
        float t10 = fmaf(2.0f, a1[0], e2v.x);                                       \
        float t11 = fmaf(2.0f, a1[1], e2v.y);                                       \
        float t12 = fmaf(2.0f, a1[2], e2v.z);                                       \
        float t13 = fmaf(2.0f, a1[3], e2v.w);                                       \
        float q0 = fminf(fminf(t00, t01), fminf(t02, t03));                         \
        float q1 = fminf(fminf(t10, t11), fminf(t12, t13));                         \
        rm0 = fminf(rm0, q0);                                                       \
        rm1 = fminf(rm1, q1);                                                       \
        if ((KT) == 0 || ((KT) & 3) == 3) {                                         \
            float s0 = fminf(rm0, __shfl_xor(rm0, 16));                             \
            s0 = fminf(s0, __shfl_xor(s0, 32));                                     \
            float s1 = fminf(rm1, __shfl_xor(rm1, 16));                             \
            s1 = fminf(s1, __shfl_xor(s1, 32));                                     \
            if (lq == 0) {                                                          \
                unsigned kk0 = fkey(s0);                                            \
                if (kk0 < m1key[lm]) atomicMin(&m1key[lm], kk0);                    \
                unsigned kk1 = fkey(s1);                                            \
                if (kk1 < m1key[16 + lm]) atomicMin(&m1key[16 + lm], kk1);          \
            }                                                                       \
            if ((KT) == 0) __syncthreads();                                         \
            thr0 = finv(m1key[lm]) + FAST_MARGIN;                                   \
            thr1 = finv(m1key[16 + lm]) + FAST_MARGIN;                              \
        }                                                                           \
        if (q0 < thr0) {                                                            \
            float tv0[4] = {t00, t01, t02, t03};                                    \
            _Pragma("unroll")                                                       \
            for (int r = 0; r < 4; ++r)                                             \
                if (tv0[r] < thr0) {                                                \
                    int pos = atomicAdd(&cnt, 1);                                   \
                    if (pos < CAP) {                                                \
                        candT[pos] = tv0[r];                                        \
                        candKX[pos] = ((unsigned)(k0 + lq * 4 + r) << 5) | lm;      \
                    } else rowbad[lm] = 1;                                          \
                }                                                                   \
        }                                                                           \
        if (q1 < thr1) {                                                            \
            float tv1[4] = {t10, t11, t12, t13};                                    \
            _Pragma("unroll")                                                       \
            for (int r = 0; r < 4; ++r)                                             \
                if (tv1[r] < thr1) {                                                \
                    int pos = atomicAdd(&cnt, 1);                                   \
                    if (pos < CAP) {                                                \
                        candT[pos] = tv1[r];                                        \
                        candKX[pos] = ((unsigned)(k0 + lq * 4 + r) << 5) | (16 + lm); \
                    } else rowbad[16 + lm] = 1;                                     \
                }                                                                   \
        }                                                                           \
    } while (0)

// ---------------- kernel 2: 2-term MFMA scores, 32 rows/block ---------------
// (256,4): the proven occupancy point — (256,6) spills (R10), bigger shapes
// spill (R12). Live state ~125 regs fits the 128 budget.
__launch_bounds__(256, 4)
__global__ void k_scores_mfma(const float* __restrict__ x, const float* __restrict__ e,
                              const float* __restrict__ e2f,
                              const unsigned char* __restrict__ eprep, float* __restrict__ out) {
    __shared__ unsigned m1key[32];
    __shared__ float    x2s[32];
    __shared__ unsigned long long finkey[32];
    __shared__ float    candT[CAP];
    __shared__ unsigned candKX[CAP];
    __shared__ int      rowbad[32];
    __shared__ int cnt;

    const int tid = threadIdx.x;
    const int w   = tid >> 6;
    const int l   = tid & 63;
    const int lq  = l >> 4;
    const int lm  = l & 15;
    const int row0 = blockIdx.x * 32;

    if (tid < 32) { m1key[tid] = 0xFFFFFFFFu; finkey[tid] = ~0ULL; rowbad[tid] = 0; }
    if (tid == 0) cnt = 0;

    // ---- X fragments (negated, hi+lo bf16) + f64 row-sum-of-squares ----
    bf16x8 bxh[2][4], bxl[2][4];
    double sx[2] = {0.0, 0.0};
#pragma unroll
    for (int f = 0; f < 2; ++f)
#pragma unroll
        for (int d = 0; d < 4; ++d) {
            const float* px = x + (size_t)(row0 + f * 16 + lm) * D_N + d * 32 + lq * 8;
            float4 a = *(const float4*)px;
            float4 b = *(const float4*)(px + 4);
            float vv[8] = {a.x, a.y, a.z, a.w, b.x, b.y, b.z, b.w};
            bf16x8 h, lo;
#pragma unroll
            for (int j = 0; j < 8; ++j) {
                float v = -vv[j];
                __bf16 hb = (__bf16)v;
                h[j] = hb;
                lo[j] = (__bf16)(v - (float)hb);
                sx[f] += (double)vv[j] * (double)vv[j];
            }
            bxh[f][d] = h; bxl[f][d] = lo;
        }
#pragma unroll
    for (int f = 0; f < 2; ++f) {
        sx[f] += __shfl_xor(sx[f], 16);
        sx[f] += __shfl_xor(sx[f], 32);
    }
    if (w == 0 && l < 16) { x2s[l] = (float)sx[0]; x2s[16 + l] = (float)sx[1]; }
    __syncthreads();   // LDS init + x2s visible

    // per-lane coalesced eprep base for this wave
    const unsigned char* ebase = eprep + (size_t)w * 4096 + (size_t)l * 16;

    // prologue: tile 0 fragments
    bf16x8 c0 = *(const bf16x8*)(ebase);
    bf16x8 c1 = *(const bf16x8*)(ebase + 1024);
    bf16x8 c2 = *(const bf16x8*)(ebase + 2048);
    bf16x8 c3 = *(const bf16x8*)(ebase + 3072);
    bf16x8 n0, n1, n2, n3;

    float rm0 = FLT_MAX, rm1 = FLT_MAX;
    float thr0 = FLT_MAX, thr1 = FLT_MAX;

    for (int kt = 0; kt < NKT; kt += 2) {
        TILE_STEP(c0, c1, c2, c3, n0, n1, n2, n3, kt);
        TILE_STEP(n0, n1, n2, n3, c0, c1, c2, c3, kt + 1);
    }
    __syncthreads();

    // ---- np-exact (SSE-order f32) eval of final-filtered candidates ----
    const int n = min(cnt, CAP);
    for (int i = tid; i < n; i += 256) {
        float tf = candT[i];
        unsigned kx = candKX[i];
        int xl = kx & 31;
        int k = kx >> 5;
        if (tf < finv(m1key[xl]) + FAST_MARGIN) {
            float tn = np_score((const float4*)(x + (size_t)(row0 + xl) * D_N),
                                (const float4*)(e + (size_t)k * D_N),
                                x2s[xl], e2f[k]);
            casMin64(&finkey[xl], ((unsigned long long)fkey(tn) << 32) | (unsigned)k);
        }
    }
    // ---- safety net: overflowed rows get a full np rescan (never expected) ----
    for (int ls = 0; ls < 32; ++ls) {
        if (!rowbad[ls]) continue;   // shared -> uniform
        for (int k = tid; k < K_N; k += 256) {
            float tn = np_score((const float4*)(x + (size_t)(row0 + ls) * D_N),
                                (const float4*)(e + (size_t)k * D_N),
                                x2s[ls], e2f[k]);
            casMin64(&finkey[ls], ((unsigned long long)fkey(tn) << 32) | (unsigned)k);
        }
    }
    __syncthreads();
    if (tid < 32) out[row0 + tid] = (float)(unsigned)(finkey[tid] & 0xFFFFFFFFull);
}

// ---------------- kernel 2 (fallback, ws too small): round-3 proven path ----
__launch_bounds__(256, 2)
__global__ void k_scores_old(const float* __restrict__ x, const float* __restrict__ e,
                             const double* __restrict__ e2d, float* __restrict__ out) {
    __shared__ float4 Xs[64 * 32];
    __shared__ float4 Es[64 * 32];
    __shared__ float  rowm1[64], rowm2[64];
    __shared__ int    rowidx[64];
    __shared__ double dbuf[256];
    __shared__ float  rv[256];
    __shared__ int    ri[256];

    const int tid = threadIdx.x;
    const int rg = tid >> 4;
    const int cg = tid & 15;
    const int row0 = blockIdx.x * 64;

    const float4* xg = (const float4*)x + (size_t)row0 * 32;
#pragma unroll
    for (int it = 0; it < 8; ++it) {
        int p = tid + it * 256;
        int r = p >> 5, f = p & 31;
        Xs[r * 32 + (f ^ ((r >> 2) & 7))] = xg[p];
    }

    float m1[4], m2[4];
    int   i1[4];
#pragma unroll
    for (int i = 0; i < 4; ++i) { m1[i] = FLT_MAX; m2[i] = FLT_MAX; i1[i] = 0; }

    for (int kt = 0; kt < K_N / 64; ++kt) {
        __syncthreads();
        const float4* eg = (const float4*)e + (size_t)kt * 64 * 32;
#pragma unroll
        for (int it = 0; it < 8; ++it) {
            int p = tid + it * 256;
            int r = p >> 5, f = p & 31;
            Es[r * 32 + (f ^ ((r >> 2) & 7))] = eg[p];
        }
        __syncthreads();

        float acc[4][4];
#pragma unroll
        for (int i = 0; i < 4; ++i)
#pragma unroll
            for (int j = 0; j < 4; ++j) acc[i][j] = 0.f;

#pragma unroll 4
        for (int f = 0; f < 32; ++f) {
            float4 xv[4], ev[4];
#pragma unroll
            for (int i = 0; i < 4; ++i) xv[i] = Xs[(rg * 4 + i) * 32 + (f ^ (rg & 7))];
#pragma unroll
            for (int j = 0; j < 4; ++j) ev[j] = Es[(cg * 4 + j) * 32 + (f ^ (cg & 7))];
#pragma unroll
            for (int i = 0; i < 4; ++i)
#pragma unroll
                for (int j = 0; j < 4; ++j) {
                    acc[i][j] = fmaf(xv[i].x, ev[j].x, acc[i][j]);
                    acc[i][j] = fmaf(xv[i].y, ev[j].y, acc[i][j]);
                    acc[i][j] = fmaf(xv[i].z, ev[j].z, acc[i][j]);
                    acc[i][j] = fmaf(xv[i].w, ev[j].w, acc[i][j]);
                }
        }

#pragma unroll
        for (int j = 0; j < 4; ++j) {
            int k = kt * 64 + cg * 4 + j;
            float e2f = (float)e2d[k];
#pragma unroll
            for (int i = 0; i < 4; ++i) {
                float t = fmaf(-2.f, acc[i][j], e2f);
                if (t < m1[i]) { m2[i] = m1[i]; m1[i] = t; i1[i] = k; }
                else if (t < m2[i]) m2[i] = t;
            }
        }
    }

#pragma unroll
    for (int off = 1; off < 16; off <<= 1) {
#pragma unroll
        for (int i = 0; i < 4; ++i) {
            float om1 = __shfl_xor(m1[i], off);
            float om2 = __shfl_xor(m2[i], off);
            int   oi1 = __shfl_xor(i1[i], off);
            bool take = (om1 < m1[i]) || (om1 == m1[i] && oi1 < i1[i]);
            float nm2 = take ? fminf(m1[i], om2) : fminf(om1, m2[i]);
            if (take) { m1[i] = om1; i1[i] = oi1; }
            m2[i] = nm2;
        }
    }

    if (cg == 0) {
#pragma unroll
        for (int i = 0; i < 4; ++i) {
            int ls = rg * 4 + i;
            rowm1[ls] = m1[i];
            rowm2[ls] = m2[i];
            rowidx[ls] = i1[i];
        }
    }
    __syncthreads();

    for (int ls = 0; ls < 64; ++ls) {
        if (!(rowm2[ls] - rowm1[ls] < 1e-4f)) continue;

        const int row = row0 + ls;
        const int sw = (ls >> 2) & 7;

        double p = 0.0;
        if (tid < D_N) { float v = x[(size_t)row * D_N + tid]; p = (double)v * (double)v; }
        dbuf[tid] = p;
        __syncthreads();
        for (int s = 128; s > 0; s >>= 1) {
            if (tid < s) dbuf[tid] += dbuf[tid + s];
            __syncthreads();
        }
        const float x2f = (float)dbuf[0];
        const double thr = (double)rowm1[ls] + 2e-4;

        float bt = FLT_MAX; int bk = 0;
        for (int k = tid; k < K_N; k += 256) {
            const float4* eg4 = (const float4*)(e + (size_t)k * D_N);
            double dot = 0.0;
#pragma unroll
            for (int f = 0; f < 32; ++f) {
                float4 ev = eg4[f];
                float4 xv = Xs[ls * 32 + (f ^ sw)];
                dot += (double)xv.x * (double)ev.x + (double)xv.y * (double)ev.y
                     + (double)xv.z * (double)ev.z + (double)xv.w * (double)ev.w;
            }
            double t64 = e2d[k] - 2.0 * dot;
            if (t64 < thr) {
                float l0 = 0.f, l1 = 0.f, l2 = 0.f, l3 = 0.f;
#pragma unroll
                for (int f = 0; f < 32; ++f) {
                    float4 ev = eg4[f];
                    float4 xv = Xs[ls * 32 + (f ^ sw)];
                    l0 = f32add(l0, f32mul(xv.x, ev.x));
                    l1 = f32add(l1, f32mul(xv.y, ev.y));
                    l2 = f32add(l2, f32mul(xv.z, ev.z));
                    l3 = f32add(l3, f32mul(xv.w, ev.w));
                }
                float xe = f32add(f32add(l0, l2), f32add(l1, l3));
                float S  = f32sub(x2f, 2.0f * xe);
                float t  = f32add(S, (float)e2d[k]);
                if (t < bt) { bt = t; bk = k; }
            }
        }
        rv[tid] = bt; ri[tid] = bk;
        __syncthreads();
        for (int s = 128; s > 0; s >>= 1) {
            if (tid < s) {
                float ov = rv[tid + s]; int oi = ri[tid + s];
                if (ov < rv[tid] || (ov == rv[tid] && oi < ri[tid])) {
                    rv[tid] = ov; ri[tid] = oi;
                }
            }
            __syncthreads();
        }
        if (tid == 0) rowidx[ls] = ri[0];
        __syncthreads();
    }

    if (tid < 64) out[row0 + tid] = (float)rowidx[tid];
}

// ------- kernel 3: gather, straight-through out, per-block loss partial ------
__global__ void k_output(const float* __restrict__ x, const float* __restrict__ e,
                         float* __restrict__ out, double* __restrict__ partials) {
    __shared__ double red[256];
    const int tid = threadIdx.x;
    const size_t base = (size_t)blockIdx.x * 1024;
    const size_t elem = base + (size_t)tid * 4;
    const int row = (int)(elem >> 7);
    const int idx = (int)out[row];

    float4 xv = *(const float4*)(x + elem);
    float4 qv = *(const float4*)(e + (size_t)idx * D_N + (elem & 127));
    float4 st;
    st.x = xv.x + (qv.x - xv.x);
    st.y = xv.y + (qv.y - xv.y);
    st.z = xv.z + (qv.z - xv.z);
    st.w = xv.w + (qv.w - xv.w);
    *(float4*)(out + (size_t)B_N + elem) = st;

    double dx = (double)xv.x - (double)qv.x;
    double dy = (double)xv.y - (double)qv.y;
    double dz = (double)xv.z - (double)qv.z;
    double dw = (double)xv.w - (double)qv.w;
    red[tid] = dx * dx + dy * dy + dz * dz + dw * dw;
    __syncthreads();
    for (int s = 128; s > 0; s >>= 1) {
        if (tid < s) red[tid] += red[tid + s];
        __syncthreads();
    }
    if (tid == 0) partials[blockIdx.x] = red[0];   // plain store, no contention
}

// ---------------- kernel 4: reduce partials, finalize scalars ----------------
__global__ void k_final(const double* __restrict__ partials, float* __restrict__ out) {
    __shared__ double red[256];
    const int tid = threadIdx.x;
    double s = 0.0;
    for (int i = tid; i < NOUTB; i += 256) s += partials[i];
    red[tid] = s;
    __syncthreads();
    for (int st = 128; st > 0; st >>= 1) {
        if (tid < st) red[tid] += red[tid + st];
        __syncthreads();
    }
    if (tid == 0) {
        double mse = red[0] / ((double)B_N * (double)D_N);
        float c = (float)mse;
        float emb = (float)mse;
        float vq = c * 0.25f + emb;
        size_t o = (size_t)B_N + (size_t)B_N * D_N;
        out[o + 0] = vq;
        out[o + 1] = emb;
        out[o + 2] = c;
    }
}

extern "C" void kernel_launch(void* const* d_in, const int* in_sizes, int n_in,
                              void* d_out, int out_size, void* d_ws, size_t ws_size,
                              hipStream_t stream) {
    const float* x = (const float*)d_in[0];
    const float* e = (const float*)d_in[1];
    float* out = (float*)d_out;

    char* ws = (char*)d_ws;
    double* e2d      = (double*)(ws + WS_E2D);
    float*  e2f      = (float*)(ws + WS_E2F);
    double* partials = (double*)(ws + WS_PART);
    unsigned char* eprep = (unsigned char*)(ws + WS_EPREP);

    const bool full = (ws_size >= WS_NEED);

    k_setup<<<K_N / 256, 256, 0, stream>>>(e, e2d, e2f, full ? 1 : 0);
    if (full) {
        k_prep_e<<<(K_N * 16) / 256, 256, 0, stream>>>(e, eprep);
        k_scores_mfma<<<B_N / 32, 256, 0, stream>>>(x, e, e2f, eprep, out);
    } else {
        k_scores_old<<<B_N / 64, 256, 0, stream>>>(x, e, e2d, out);
    }
    k_output<<<NOUTB, 256, 0, stream>>>(x, e, out, partials);
    k_final<<<1, 256, 0, stream>>>(partials, out);
}

// Round 14
// 199.938 us; speedup vs baseline: 1.5899x; 1.5899x over previous
//
#include <hip/hip_runtime.h>
#include <cfloat>

#define B_N 65536
#define D_N 128
#define K_N 4096
#define NKT (K_N / 64)
#define NOUTB ((B_N * D_N) / 1024)   // k_output blocks = 8192

// 2-term split-bf16 fast score: t_fast = e2 - 2*(xhi+xlo)·ehi. (proven R7-R9)
// Margin covers np-f32 grid tie window (~3.2e-5) + dropped x·elo term (10 sigma).
#define FAST_MARGIN 1e-4f
#define CAP 768

typedef __bf16 bf16x8 __attribute__((ext_vector_type(8)));
typedef float  f32x4  __attribute__((ext_vector_type(4)));

// ---------------- workspace layout (bytes) ----------------
static constexpr size_t WS_E2D   = 0;                           // double[K_N]
static constexpr size_t WS_E2F   = WS_E2D + 8 * (size_t)K_N;    // float[K_N]
static constexpr size_t WS_PART  = WS_E2F + 4 * (size_t)K_N;    // double[NOUTB]
static constexpr size_t WS_EPREP = WS_PART + 8 * (size_t)NOUTB; // 64 tiles x 16KB
static constexpr size_t WS_NEED  = WS_EPREP + (size_t)NKT * 16384;

// correctly-rounded f32 ops emulated via f64 (uncontractible)
__device__ __forceinline__ float f32mul(float a, float b) { return (float)((double)a * (double)b); }
__device__ __forceinline__ float f32add(float a, float b) { return (float)((double)a + (double)b); }
__device__ __forceinline__ float f32sub(float a, float b) { return (float)((double)a - (double)b); }

// monotone float<->uint key (no NaNs in scores)
__device__ __forceinline__ unsigned fkey(float f) {
    unsigned u = __float_as_uint(f);
    return (u & 0x80000000u) ? ~u : (u | 0x80000000u);
}
__device__ __forceinline__ float finv(unsigned k) {
    return __uint_as_float((k & 0x80000000u) ? (k ^ 0x80000000u) : ~k);
}

__device__ __forceinline__ void casMin64(unsigned long long* p, unsigned long long v) {
    unsigned long long old = *p;
    while (v < old) {
        unsigned long long prev = atomicCAS(p, old, v);
        if (prev == old) break;
        old = prev;
    }
}

// numpy einsum SSE-order f32 dot emulation + final score (proven exact vs np)
__device__ __forceinline__ float np_score(const float4* __restrict__ xr,
                                          const float4* __restrict__ er,
                                          float x2, float e2) {
    float l0 = 0.f, l1 = 0.f, l2 = 0.f, l3 = 0.f;
#pragma unroll
    for (int f = 0; f < 32; ++f) {
        float4 xv = xr[f];
        float4 ev = er[f];
        l0 = f32add(l0, f32mul(xv.x, ev.x));
        l1 = f32add(l1, f32mul(xv.y, ev.y));
        l2 = f32add(l2, f32mul(xv.z, ev.z));
        l3 = f32add(l3, f32mul(xv.w, ev.w));
    }
    float xe = f32add(f32add(l0, l2), f32add(l1, l3));
    float S  = f32sub(x2, 2.0f * xe);
    return f32add(S, e2);
}

// ---------------- kernel 1: e2 (f64 + f32) ----------------
__global__ void k_setup(const float* __restrict__ e, double* __restrict__ e2d,
                        float* __restrict__ e2f, int full) {
    int k = blockIdx.x * blockDim.x + threadIdx.x;
    if (k < K_N) {
        const float* row = e + (size_t)k * D_N;
        double s = 0.0;
        for (int d = 0; d < D_N; ++d) { double v = (double)row[d]; s += v * v; }
        e2d[k] = s;
        if (full) e2f[k] = (float)s;
    }
}

// ---------------- kernel 1c: E -> bf16-hi fragments in per-lane order -------
// addr(kt, w, c, lane) = kt*16384 + w*4096 + c*1024 + lane*16.
// Content: bf16x8 of e[row = kt*64 + w*16 + (lane&15)][d = c*32 + (lane>>4)*8 ..+8].
// Every k_scores fragment load becomes one contiguous 1KB wave read.
__global__ void k_prep_e(const float* __restrict__ e, unsigned char* __restrict__ eprep) {
    const int g = blockIdx.x * 256 + threadIdx.x;   // one 16B chunk; 65536 total
    const int kt   = g >> 10;
    const int q    = g & 1023;
    const int w    = q >> 8;
    const int c    = (q >> 6) & 3;
    const int lane = q & 63;
    const int r  = kt * 64 + w * 16 + (lane & 15);
    const int d0 = c * 32 + (lane >> 4) * 8;
    const float* src = e + (size_t)r * D_N + d0;
    float4 a = *(const float4*)src;
    float4 b = *(const float4*)(src + 4);
    bf16x8 h;
    h[0] = (__bf16)a.x; h[1] = (__bf16)a.y; h[2] = (__bf16)a.z; h[3] = (__bf16)a.w;
    h[4] = (__bf16)b.x; h[5] = (__bf16)b.y; h[6] = (__bf16)b.z; h[7] = (__bf16)b.w;
    *(bf16x8*)(eprep + (size_t)g * 16) = h;
}

// ---------------- kernel 2: 2-term MFMA scores (R9-exact, proven 184 us) ----
// block: 256 thr (4 waves), 32 x-rows. Wave w owns e-rows [kt*64+w*16, +16).
// A = E-hi (coalesced per-lane loads from eprep, reg double-buffered);
// B = -X hi/lo in regs. acc = -(xhi+xlo).ehi => t = 2*acc + e2.
// Running row-min in LDS; near-min candidates appended; np-exact eval at end.
// x2 computed in-kernel (f64) from fragment source data.
__launch_bounds__(256, 4)
__global__ void k_scores_mfma(const float* __restrict__ x, const float* __restrict__ e,
                              const float* __restrict__ e2f,
                              const unsigned char* __restrict__ eprep, float* __restrict__ out) {
    __shared__ unsigned m1key[32];
    __shared__ float    x2s[32];
    __shared__ unsigned long long finkey[32];
    __shared__ float    candT[CAP];
    __shared__ unsigned candKX[CAP];
    __shared__ int      rowbad[32];
    __shared__ int cnt;

    const int tid = threadIdx.x;
    const int w   = tid >> 6;
    const int l   = tid & 63;
    const int lq  = l >> 4;
    const int lm  = l & 15;
    const int row0 = blockIdx.x * 32;

    if (tid < 32) { m1key[tid] = 0xFFFFFFFFu; finkey[tid] = ~0ULL; rowbad[tid] = 0; }
    if (tid == 0) cnt = 0;

    // ---- X fragments (negated, hi+lo bf16) + f64 row-sum-of-squares ----
    bf16x8 bxh[2][4], bxl[2][4];
    double sx[2] = {0.0, 0.0};
#pragma unroll
    for (int f = 0; f < 2; ++f)
#pragma unroll
        for (int d = 0; d < 4; ++d) {
            const float* px = x + (size_t)(row0 + f * 16 + lm) * D_N + d * 32 + lq * 8;
            float4 a = *(const float4*)px;
            float4 b = *(const float4*)(px + 4);
            float vv[8] = {a.x, a.y, a.z, a.w, b.x, b.y, b.z, b.w};
            bf16x8 h, lo;
#pragma unroll
            for (int j = 0; j < 8; ++j) {
                float v = -vv[j];
                __bf16 hb = (__bf16)v;
                h[j] = hb;
                lo[j] = (__bf16)(v - (float)hb);
                sx[f] += (double)vv[j] * (double)vv[j];
            }
            bxh[f][d] = h; bxl[f][d] = lo;
        }
    // reduce x2 across the 4 lq lanes sharing a row; wave 0 publishes
#pragma unroll
    for (int f = 0; f < 2; ++f) {
        sx[f] += __shfl_xor(sx[f], 16);
        sx[f] += __shfl_xor(sx[f], 32);
    }
    if (w == 0 && l < 16) { x2s[l] = (float)sx[0]; x2s[16 + l] = (float)sx[1]; }
    __syncthreads();   // LDS init + x2s visible

    // per-lane coalesced eprep base for this wave
    const unsigned char* ebase = eprep + (size_t)w * 4096 + (size_t)l * 16;

    // prologue: tile 0 fragments
    bf16x8 c0 = *(const bf16x8*)(ebase);
    bf16x8 c1 = *(const bf16x8*)(ebase + 1024);
    bf16x8 c2 = *(const bf16x8*)(ebase + 2048);
    bf16x8 c3 = *(const bf16x8*)(ebase + 3072);

    for (int kt = 0; kt < NKT; ++kt) {
        // e2 for this tile (consumed after MFMA -> latency self-hidden)
        const int k0 = kt * 64 + w * 16;
        float4 e2v = *(const float4*)(e2f + k0 + lq * 4);

        // T14: issue next tile's fragment loads early
        bf16x8 n0 = c0, n1 = c1, n2 = c2, n3 = c3;
        if (kt + 1 < NKT) {
            const unsigned char* bp = ebase + (size_t)(kt + 1) * 16384;
            n0 = *(const bf16x8*)(bp);
            n1 = *(const bf16x8*)(bp + 1024);
            n2 = *(const bf16x8*)(bp + 2048);
            n3 = *(const bf16x8*)(bp + 3072);
        }

        f32x4 acc[2] = {};
        acc[0] = __builtin_amdgcn_mfma_f32_16x16x32_bf16(c0, bxh[0][0], acc[0], 0, 0, 0);
        acc[1] = __builtin_amdgcn_mfma_f32_16x16x32_bf16(c0, bxh[1][0], acc[1], 0, 0, 0);
        acc[0] = __builtin_amdgcn_mfma_f32_16x16x32_bf16(c0, bxl[0][0], acc[0], 0, 0, 0);
        acc[1] = __builtin_amdgcn_mfma_f32_16x16x32_bf16(c0, bxl[1][0], acc[1], 0, 0, 0);
        acc[0] = __builtin_amdgcn_mfma_f32_16x16x32_bf16(c1, bxh[0][1], acc[0], 0, 0, 0);
        acc[1] = __builtin_amdgcn_mfma_f32_16x16x32_bf16(c1, bxh[1][1], acc[1], 0, 0, 0);
        acc[0] = __builtin_amdgcn_mfma_f32_16x16x32_bf16(c1, bxl[0][1], acc[0], 0, 0, 0);
        acc[1] = __builtin_amdgcn_mfma_f32_16x16x32_bf16(c1, bxl[1][1], acc[1], 0, 0, 0);
        acc[0] = __builtin_amdgcn_mfma_f32_16x16x32_bf16(c2, bxh[0][2], acc[0], 0, 0, 0);
        acc[1] = __builtin_amdgcn_mfma_f32_16x16x32_bf16(c2, bxh[1][2], acc[1], 0, 0, 0);
        acc[0] = __builtin_amdgcn_mfma_f32_16x16x32_bf16(c2, bxl[0][2], acc[0], 0, 0, 0);
        acc[1] = __builtin_amdgcn_mfma_f32_16x16x32_bf16(c2, bxl[1][2], acc[1], 0, 0, 0);
        acc[0] = __builtin_amdgcn_mfma_f32_16x16x32_bf16(c3, bxh[0][3], acc[0], 0, 0, 0);
        acc[1] = __builtin_amdgcn_mfma_f32_16x16x32_bf16(c3, bxh[1][3], acc[1], 0, 0, 0);
        acc[0] = __builtin_amdgcn_mfma_f32_16x16x32_bf16(c3, bxl[0][3], acc[0], 0, 0, 0);
        acc[1] = __builtin_amdgcn_mfma_f32_16x16x32_bf16(c3, bxl[1][3], acc[1], 0, 0, 0);

        // ---- epilogue: t = 2*acc + e2, running row-min fold ----
        float t[2][4];
#pragma unroll
        for (int f = 0; f < 2; ++f) {
            t[f][0] = fmaf(2.0f, acc[f][0], e2v.x);
            t[f][1] = fmaf(2.0f, acc[f][1], e2v.y);
            t[f][2] = fmaf(2.0f, acc[f][2], e2v.z);
            t[f][3] = fmaf(2.0f, acc[f][3], e2v.w);
            float tmin = fminf(fminf(t[f][0], t[f][1]), fminf(t[f][2], t[f][3]));
            tmin = fminf(tmin, __shfl_xor(tmin, 16));
            tmin = fminf(tmin, __shfl_xor(tmin, 32));
            if (lq == 0) {
                unsigned kk = fkey(tmin);
                if (kk < m1key[f * 16 + lm]) atomicMin(&m1key[f * 16 + lm], kk);
            }
        }
        if (kt == 0) __syncthreads();   // seed global row-min before first appends

        // ---- append near-min candidates (stale min => superset, safe) ----
#pragma unroll
        for (int f = 0; f < 2; ++f) {
            const int xl = f * 16 + lm;
            float thr = finv(m1key[xl]) + FAST_MARGIN;
#pragma unroll
            for (int r = 0; r < 4; ++r) {
                if (t[f][r] < thr) {
                    int pos = atomicAdd(&cnt, 1);
                    if (pos < CAP) {
                        candT[pos] = t[f][r];
                        candKX[pos] = ((unsigned)(k0 + lq * 4 + r) << 5) | (unsigned)xl;
                    } else {
                        rowbad[xl] = 1;
                    }
                }
            }
        }
        c0 = n0; c1 = n1; c2 = n2; c3 = n3;
    }
    __syncthreads();

    // ---- np-exact (SSE-order f32) eval of final-filtered candidates ----
    const int n = min(cnt, CAP);
    for (int i = tid; i < n; i += 256) {
        float tf = candT[i];
        unsigned kx = candKX[i];
        int xl = kx & 31;
        int k = kx >> 5;
        if (tf < finv(m1key[xl]) + FAST_MARGIN) {
            float tn = np_score((const float4*)(x + (size_t)(row0 + xl) * D_N),
                                (const float4*)(e + (size_t)k * D_N),
                                x2s[xl], e2f[k]);
            casMin64(&finkey[xl], ((unsigned long long)fkey(tn) << 32) | (unsigned)k);
        }
    }
    // ---- safety net: overflowed rows get a full np rescan (never expected) ----
    for (int ls = 0; ls < 32; ++ls) {
        if (!rowbad[ls]) continue;   // shared -> uniform
        for (int k = tid; k < K_N; k += 256) {
            float tn = np_score((const float4*)(x + (size_t)(row0 + ls) * D_N),
                                (const float4*)(e + (size_t)k * D_N),
                                x2s[ls], e2f[k]);
            casMin64(&finkey[ls], ((unsigned long long)fkey(tn) << 32) | (unsigned)k);
        }
    }
    __syncthreads();
    if (tid < 32) out[row0 + tid] = (float)(unsigned)(finkey[tid] & 0xFFFFFFFFull);
}

// ---------------- kernel 2 (fallback, ws too small): round-3 proven path ----
__launch_bounds__(256, 2)
__global__ void k_scores_old(const float* __restrict__ x, const float* __restrict__ e,
                             const double* __restrict__ e2d, float* __restrict__ out) {
    __shared__ float4 Xs[64 * 32];
    __shared__ float4 Es[64 * 32];
    __shared__ float  rowm1[64], rowm2[64];
    __shared__ int    rowidx[64];
    __shared__ double dbuf[256];
    __shared__ float  rv[256];
    __shared__ int    ri[256];

    const int tid = threadIdx.x;
    const int rg = tid >> 4;
    const int cg = tid & 15;
    const int row0 = blockIdx.x * 64;

    const float4* xg = (const float4*)x + (size_t)row0 * 32;
#pragma unroll
    for (int it = 0; it < 8; ++it) {
        int p = tid + it * 256;
        int r = p >> 5, f = p & 31;
        Xs[r * 32 + (f ^ ((r >> 2) & 7))] = xg[p];
    }

    float m1[4], m2[4];
    int   i1[4];
#pragma unroll
    for (int i = 0; i < 4; ++i) { m1[i] = FLT_MAX; m2[i] = FLT_MAX; i1[i] = 0; }

    for (int kt = 0; kt < K_N / 64; ++kt) {
        __syncthreads();
        const float4* eg = (const float4*)e + (size_t)kt * 64 * 32;
#pragma unroll
        for (int it = 0; it < 8; ++it) {
            int p = tid + it * 256;
            int r = p >> 5, f = p & 31;
            Es[r * 32 + (f ^ ((r >> 2) & 7))] = eg[p];
        }
        __syncthreads();

        float acc[4][4];
#pragma unroll
        for (int i = 0; i < 4; ++i)
#pragma unroll
            for (int j = 0; j < 4; ++j) acc[i][j] = 0.f;

#pragma unroll 4
        for (int f = 0; f < 32; ++f) {
            float4 xv[4], ev[4];
#pragma unroll
            for (int i = 0; i < 4; ++i) xv[i] = Xs[(rg * 4 + i) * 32 + (f ^ (rg & 7))];
#pragma unroll
            for (int j = 0; j < 4; ++j) ev[j] = Es[(cg * 4 + j) * 32 + (f ^ (cg & 7))];
#pragma unroll
            for (int i = 0; i < 4; ++i)
#pragma unroll
                for (int j = 0; j < 4; ++j) {
                    acc[i][j] = fmaf(xv[i].x, ev[j].x, acc[i][j]);
                    acc[i][j] = fmaf(xv[i].y, ev[j].y, acc[i][j]);
                    acc[i][j] = fmaf(xv[i].z, ev[j].z, acc[i][j]);
                    acc[i][j] = fmaf(xv[i].w, ev[j].w, acc[i][j]);
                }
        }

#pragma unroll
        for (int j = 0; j < 4; ++j) {
            int k = kt * 64 + cg * 4 + j;
            float e2f = (float)e2d[k];
#pragma unroll
            for (int i = 0; i < 4; ++i) {
                float t = fmaf(-2.f, acc[i][j], e2f);
                if (t < m1[i]) { m2[i] = m1[i]; m1[i] = t; i1[i] = k; }
                else if (t < m2[i]) m2[i] = t;
            }
        }
    }

#pragma unroll
    for (int off = 1; off < 16; off <<= 1) {
#pragma unroll
        for (int i = 0; i < 4; ++i) {
            float om1 = __shfl_xor(m1[i], off);
            float om2 = __shfl_xor(m2[i], off);
            int   oi1 = __shfl_xor(i1[i], off);
            bool take = (om1 < m1[i]) || (om1 == m1[i] && oi1 < i1[i]);
            float nm2 = take ? fminf(m1[i], om2) : fminf(om1, m2[i]);
            if (take) { m1[i] = om1; i1[i] = oi1; }
            m2[i] = nm2;
        }
    }

    if (cg == 0) {
#pragma unroll
        for (int i = 0; i < 4; ++i) {
            int ls = rg * 4 + i;
            rowm1[ls] = m1[i];
            rowm2[ls] = m2[i];
            rowidx[ls] = i1[i];
        }
    }
    __syncthreads();

    for (int ls = 0; ls < 64; ++ls) {
        if (!(rowm2[ls] - rowm1[ls] < 1e-4f)) continue;

        const int row = row0 + ls;
        const int sw = (ls >> 2) & 7;

        double p = 0.0;
        if (tid < D_N) { float v = x[(size_t)row * D_N + tid]; p = (double)v * (double)v; }
        dbuf[tid] = p;
        __syncthreads();
        for (int s = 128; s > 0; s >>= 1) {
            if (tid < s) dbuf[tid] += dbuf[tid + s];
            __syncthreads();
        }
        const float x2f = (float)dbuf[0];
        const double thr = (double)rowm1[ls] + 2e-4;

        float bt = FLT_MAX; int bk = 0;
        for (int k = tid; k < K_N; k += 256) {
            const float4* eg4 = (const float4*)(e + (size_t)k * D_N);
            double dot = 0.0;
#pragma unroll
            for (int f = 0; f < 32; ++f) {
                float4 ev = eg4[f];
                float4 xv = Xs[ls * 32 + (f ^ sw)];
                dot += (double)xv.x * (double)ev.x + (double)xv.y * (double)ev.y
                     + (double)xv.z * (double)ev.z + (double)xv.w * (double)ev.w;
            }
            double t64 = e2d[k] - 2.0 * dot;
            if (t64 < thr) {
                float l0 = 0.f, l1 = 0.f, l2 = 0.f, l3 = 0.f;
#pragma unroll
                for (int f = 0; f < 32; ++f) {
                    float4 ev = eg4[f];
                    float4 xv = Xs[ls * 32 + (f ^ sw)];
                    l0 = f32add(l0, f32mul(xv.x, ev.x));
                    l1 = f32add(l1, f32mul(xv.y, ev.y));
                    l2 = f32add(l2, f32mul(xv.z, ev.z));
                    l3 = f32add(l3, f32mul(xv.w, ev.w));
                }
                float xe = f32add(f32add(l0, l2), f32add(l1, l3));
                float S  = f32sub(x2f, 2.0f * xe);
                float t  = f32add(S, (float)e2d[k]);
                if (t < bt) { bt = t; bk = k; }
            }
        }
        rv[tid] = bt; ri[tid] = bk;
        __syncthreads();
        for (int s = 128; s > 0; s >>= 1) {
            if (tid < s) {
                float ov = rv[tid + s]; int oi = ri[tid + s];
                if (ov < rv[tid] || (ov == rv[tid] && oi < ri[tid])) {
                    rv[tid] = ov; ri[tid] = oi;
                }
            }
            __syncthreads();
        }
        if (tid == 0) rowidx[ls] = ri[0];
        __syncthreads();
    }

    if (tid < 64) out[row0 + tid] = (float)rowidx[tid];
}

// ------- kernel 3: gather, straight-through out, per-block loss partial ------
__global__ void k_output(const float* __restrict__ x, const float* __restrict__ e,
                         float* __restrict__ out, double* __restrict__ partials) {
    __shared__ double red[256];
    const int tid = threadIdx.x;
    const size_t base = (size_t)blockIdx.x * 1024;
    const size_t elem = base + (size_t)tid * 4;
    const int row = (int)(elem >> 7);
    const int idx = (int)out[row];

    float4 xv = *(const float4*)(x + elem);
    float4 qv = *(const float4*)(e + (size_t)idx * D_N + (elem & 127));
    float4 st;
    st.x = xv.x + (qv.x - xv.x);
    st.y = xv.y + (qv.y - xv.y);
    st.z = xv.z + (qv.z - xv.z);
    st.w = xv.w + (qv.w - xv.w);
    *(float4*)(out + (size_t)B_N + elem) = st;

    double dx = (double)xv.x - (double)qv.x;
    double dy = (double)xv.y - (double)qv.y;
    double dz = (double)xv.z - (double)qv.z;
    double dw = (double)xv.w - (double)qv.w;
    red[tid] = dx * dx + dy * dy + dz * dz + dw * dw;
    __syncthreads();
    for (int s = 128; s > 0; s >>= 1) {
        if (tid < s) red[tid] += red[tid + s];
        __syncthreads();
    }
    if (tid == 0) partials[blockIdx.x] = red[0];   // plain store, no contention
}

// ---------------- kernel 4: reduce partials, finalize scalars ----------------
__global__ void k_final(const double* __restrict__ partials, float* __restrict__ out) {
    __shared__ double red[256];
    const int tid = threadIdx.x;
    double s = 0.0;
    for (int i = tid; i < NOUTB; i += 256) s += partials[i];
    red[tid] = s;
    __syncthreads();
    for (int st = 128; st > 0; st >>= 1) {
        if (tid < st) red[tid] += red[tid + st];
        __syncthreads();
    }
    if (tid == 0) {
        double mse = red[0] / ((double)B_N * (double)D_N);
        float c = (float)mse;
        float emb = (float)mse;
        float vq = c * 0.25f + emb;
        size_t o = (size_t)B_N + (size_t)B_N * D_N;
        out[o + 0] = vq;
        out[o + 1] = emb;
        out[o + 2] = c;
    }
}

extern "C" void kernel_launch(void* const* d_in, const int* in_sizes, int n_in,
                              void* d_out, int out_size, void* d_ws, size_t ws_size,
                              hipStream_t stream) {
    const float* x = (const float*)d_in[0];
    const float* e = (const float*)d_in[1];
    float* out = (float*)d_out;

    char* ws = (char*)d_ws;
    double* e2d      = (double*)(ws + WS_E2D);
    float*  e2f      = (float*)(ws + WS_E2F);
    double* partials = (double*)(ws + WS_PART);
    unsigned char* eprep = (unsigned char*)(ws + WS_EPREP);

    const bool full = (ws_size >= WS_NEED);

    k_setup<<<K_N / 256, 256, 0, stream>>>(e, e2d, e2f, full ? 1 : 0);
    if (full) {
        k_prep_e<<<(K_N * 16) / 256, 256, 0, stream>>>(e, eprep);
        k_scores_mfma<<<B_N / 32, 256, 0, stream>>>(x, e, e2f, eprep, out);
    } else {
        k_scores_old<<<B_N / 64, 256, 0, stream>>>(x, e, e2d, out);
    }
    k_output<<<NOUTB, 256, 0, stream>>>(x, e, out, partials);
    k_final<<<1, 256, 0, stream>>>(partials, out);
}